// Round 1
// baseline (251.171 us; speedup 1.0000x reference)
//
#include <hip/hip_runtime.h>

// SMPL2MeshOptimizer: fused mesh loss on MI355X.
// ws layout (floats): acc[16] | nbr_sum[3V] | deg[V] | vsum[3V] (all zeroed)
//                     | minbuf[Ns+Nt+V] (u32, 0xFF init)
//                     | new_verts[3V] | sample_src[3Ns] | fn_unit[3F] | e012[3F] | elen[E]
// Total ~2.1 MB.

#define MEPS 1e-6f

__device__ __forceinline__ float waveReduceAdd(float v) {
#pragma unroll
  for (int off = 32; off > 0; off >>= 1) v += __shfl_down(v, off, 64);
  return v;
}
__device__ __forceinline__ void blockAccum(float* dst, float v) {
  v = waveReduceAdd(v);
  if ((threadIdx.x & 63) == 0) atomicAdd(dst, v);
}
// monotonic float<->uint mapping so atomicMin(u32) == float min (handles negatives)
__device__ __forceinline__ unsigned f2sort(float f) {
  unsigned b = __float_as_uint(f);
  return (b & 0x80000000u) ? ~b : (b | 0x80000000u);
}
__device__ __forceinline__ float sort2f(unsigned s) {
  unsigned b = (s & 0x80000000u) ? (s & 0x7fffffffu) : ~s;
  return __uint_as_float(b);
}

// ---- K1: new_verts = verts + deform; penetration term ----
__global__ __launch_bounds__(256)
void k_prep_verts(const float* __restrict__ verts, const float* __restrict__ deform,
                  const float* __restrict__ vnorm, float* __restrict__ new_verts,
                  float* __restrict__ acc) {
  int i = blockIdx.x * 256 + threadIdx.x;
  float dx = deform[3*i], dy = deform[3*i+1], dz = deform[3*i+2];
  float nx = verts[3*i] + dx, ny = verts[3*i+1] + dy, nz = verts[3*i+2] + dz;
  new_verts[3*i] = nx; new_verts[3*i+1] = ny; new_verts[3*i+2] = nz;
  float dot = dx*vnorm[3*i] + dy*vnorm[3*i+1] + dz*vnorm[3*i+2];
  float pen = fabsf(fminf(dot, -0.1f));
  blockAccum(&acc[11], pen);
}

// ---- K2: faces pass 1: edge lengths, face normals, smooth, vsum scatter ----
__global__ __launch_bounds__(256)
void k_faces1(const int* __restrict__ faces, const float* __restrict__ nv,
              const float* __restrict__ deform, float* __restrict__ e012,
              float* __restrict__ fn_unit, float* __restrict__ vsum,
              float* __restrict__ acc, int F) {
  int f = blockIdx.x * 256 + threadIdx.x;
  int i0 = faces[3*f], i1 = faces[3*f+1], i2 = faces[3*f+2];
  float v0x = nv[3*i0], v0y = nv[3*i0+1], v0z = nv[3*i0+2];
  float v1x = nv[3*i1], v1y = nv[3*i1+1], v1z = nv[3*i1+2];
  float v2x = nv[3*i2], v2y = nv[3*i2+1], v2z = nv[3*i2+2];
  float e0 = sqrtf((v0x-v1x)*(v0x-v1x) + (v0y-v1y)*(v0y-v1y) + (v0z-v1z)*(v0z-v1z));
  float e1 = sqrtf((v1x-v2x)*(v1x-v2x) + (v1y-v2y)*(v1y-v2y) + (v1z-v2z)*(v1z-v2z));
  float e2 = sqrtf((v2x-v0x)*(v2x-v0x) + (v2y-v0y)*(v2y-v0y) + (v2z-v0z)*(v2z-v0z));
  e012[f] = e0; e012[F+f] = e1; e012[2*F+f] = e2;
  // fn = cross(v1-v0, v2-v0)
  float ax = v1x-v0x, ay = v1y-v0y, az = v1z-v0z;
  float bx = v2x-v0x, by = v2y-v0y, bz = v2z-v0z;
  float fnx = ay*bz - az*by, fny = az*bx - ax*bz, fnz = ax*by - ay*bx;
  float fl = sqrtf(fnx*fnx + fny*fny + fnz*fnz);
  float inv = 1.0f / (fl + MEPS);
  fn_unit[3*f] = fnx*inv; fn_unit[3*f+1] = fny*inv; fn_unit[3*f+2] = fnz*inv;
  // consistency scatter: raw fn to each face vertex
  atomicAdd(&vsum[3*i0], fnx); atomicAdd(&vsum[3*i0+1], fny); atomicAdd(&vsum[3*i0+2], fnz);
  atomicAdd(&vsum[3*i1], fnx); atomicAdd(&vsum[3*i1+1], fny); atomicAdd(&vsum[3*i1+2], fnz);
  atomicAdd(&vsum[3*i2], fnx); atomicAdd(&vsum[3*i2+1], fny); atomicAdd(&vsum[3*i2+2], fnz);
  // smooth: s_k = ||deform[ik]||
  float s0 = sqrtf(deform[3*i0]*deform[3*i0] + deform[3*i0+1]*deform[3*i0+1] + deform[3*i0+2]*deform[3*i0+2]);
  float s1 = sqrtf(deform[3*i1]*deform[3*i1] + deform[3*i1+1]*deform[3*i1+1] + deform[3*i1+2]*deform[3*i1+2]);
  float s2 = sqrtf(deform[3*i2]*deform[3*i2] + deform[3*i2+1]*deform[3*i2+1] + deform[3*i2+2]*deform[3*i2+2]);
  blockAccum(&acc[5], fabsf(s0-s1) + fabsf(s1-s2) + fabsf(s2-s0));
  blockAccum(&acc[0], e0 + e1 + e2);
  blockAccum(&acc[1], fabsf(e0-e1) + fabsf(e1-e2) + fabsf(e2-e0));
}

// ---- K3: edges pass 1: elen + laplacian scatter ----
__global__ __launch_bounds__(256)
void k_edges1(const int* __restrict__ edges, const float* __restrict__ nv,
              float* __restrict__ elen, float* __restrict__ nbr,
              float* __restrict__ deg, int E) {
  int e = blockIdx.x * 256 + threadIdx.x;
  int a = edges[2*e], b = edges[2*e+1];
  float pax = nv[3*a], pay = nv[3*a+1], paz = nv[3*a+2];
  float pbx = nv[3*b], pby = nv[3*b+1], pbz = nv[3*b+2];
  elen[e] = sqrtf((pax-pbx)*(pax-pbx) + (pay-pby)*(pay-pby) + (paz-pbz)*(paz-pbz));
  atomicAdd(&nbr[3*a], pbx); atomicAdd(&nbr[3*a+1], pby); atomicAdd(&nbr[3*a+2], pbz);
  atomicAdd(&nbr[3*b], pax); atomicAdd(&nbr[3*b+1], pay); atomicAdd(&nbr[3*b+2], paz);
  atomicAdd(&deg[a], 1.0f);  atomicAdd(&deg[b], 1.0f);
}

// ---- K4: sample_src = bary-weighted face vertices ----
__global__ __launch_bounds__(256)
void k_sample(const int* __restrict__ sfi, const int* __restrict__ faces,
              const float* __restrict__ bary, const float* __restrict__ nv,
              float* __restrict__ s_src) {
  int s = blockIdx.x * 256 + threadIdx.x;
  int f = sfi[s];
  int i0 = faces[3*f], i1 = faces[3*f+1], i2 = faces[3*f+2];
  float w0 = bary[3*s], w1 = bary[3*s+1], w2 = bary[3*s+2];
  s_src[3*s]   = w0*nv[3*i0]   + w1*nv[3*i1]   + w2*nv[3*i2];
  s_src[3*s+1] = w0*nv[3*i0+1] + w1*nv[3*i1+1] + w2*nv[3*i2+1];
  s_src[3*s+2] = w0*nv[3*i0+2] + w1*nv[3*i1+2] + w2*nv[3*i2+2];
}

// ---- K5: normal loss over face pairs ----
__global__ __launch_bounds__(256)
void k_pairs(const int* __restrict__ fp, const float* __restrict__ fn_unit,
             float* __restrict__ acc) {
  int p = blockIdx.x * 256 + threadIdx.x;
  int f0 = fp[2*p], f1 = fp[2*p+1];
  float d = fn_unit[3*f0]*fn_unit[3*f1] + fn_unit[3*f0+1]*fn_unit[3*f1+1]
          + fn_unit[3*f0+2]*fn_unit[3*f1+2];
  blockAccum(&acc[4], 1.0f - d);
}

// ---- K6: pass 2 over faces (|e-avg|) and edges ((elen-avg)^2) ----
__global__ __launch_bounds__(256)
void k_pass2(const float* __restrict__ e012, const float* __restrict__ elen,
             float* __restrict__ acc, int F) {
  int idx = blockIdx.x * 256 + threadIdx.x;
  float avg = acc[0] / (3.0f * (float)F);
  if (idx < F) {
    float e0 = e012[idx], e1 = e012[F+idx], e2 = e012[2*F+idx];
    blockAccum(&acc[2], fabsf(e0-avg) + fabsf(e1-avg) + fabsf(e2-avg));
  } else {
    int e = idx - F;
    float d = elen[e] - avg;
    blockAccum(&acc[3], d*d);
  }
}

// ---- K7: per-vertex finalize: laplacian norm + consistency ----
__global__ __launch_bounds__(256)
void k_vfin(const float* __restrict__ nbr, const float* __restrict__ deg,
            const float* __restrict__ vsum, const float* __restrict__ nv,
            const float* __restrict__ vnorm, float* __restrict__ acc) {
  int i = blockIdx.x * 256 + threadIdx.x;
  float inv = 1.0f / fmaxf(deg[i], 1.0f);
  float lx = nbr[3*i]*inv   - nv[3*i];
  float ly = nbr[3*i+1]*inv - nv[3*i+1];
  float lz = nbr[3*i+2]*inv - nv[3*i+2];
  blockAccum(&acc[6], sqrtf(lx*lx + ly*ly + lz*lz));
  float vx = vsum[3*i], vy = vsum[3*i+1], vz = vsum[3*i+2];
  float vinv = 1.0f / (sqrtf(vx*vx + vy*vy + vz*vz) + MEPS);
  float dx = vx*vinv - vnorm[3*i];
  float dy = vy*vinv - vnorm[3*i+1];
  float dz = vz*vinv - vnorm[3*i+2];
  blockAccum(&acc[7], dx*dx + dy*dy + dz*dz);
}

// ---- Chamfer min: block = 1024 a-points (4/thread) x 1024 b-points in LDS ----
#define CTB 1024
__global__ __launch_bounds__(256)
void k_cham(const float* __restrict__ A, const float* __restrict__ B,
            unsigned* __restrict__ minbuf, float flipSign) {
  __shared__ float lds[CTB * 4];
  int tid = threadIdx.x;
  int aBase = blockIdx.x * 1024;
  int b0 = blockIdx.y * CTB;
  float ax[4], ay[4], az[4], m[4];
#pragma unroll
  for (int r = 0; r < 4; ++r) {
    int ai = aBase + r*256 + tid;
    ax[r] = A[3*ai]; ay[r] = A[3*ai+1]; az[r] = A[3*ai+2];
    m[r] = 3.402823466e38f;
  }
#pragma unroll
  for (int k = 0; k < CTB/256; ++k) {
    int j = k*256 + tid;
    int bi = b0 + j;
    float bx = B[3*bi] * flipSign;
    float by = B[3*bi+1];
    float bz = B[3*bi+2];
    float bs = bx*bx + by*by + bz*bz;
    *reinterpret_cast<float4*>(&lds[4*j]) = make_float4(-2.0f*bx, -2.0f*by, -2.0f*bz, bs);
  }
  __syncthreads();
#pragma unroll 8
  for (int j = 0; j < CTB; ++j) {
    float4 b = *reinterpret_cast<const float4*>(&lds[4*j]);
#pragma unroll
    for (int r = 0; r < 4; ++r) {
      float t = fmaf(ax[r], b.x, fmaf(ay[r], b.y, fmaf(az[r], b.z, b.w)));
      m[r] = fminf(m[r], t);
    }
  }
#pragma unroll
  for (int r = 0; r < 4; ++r) {
    int ai = aBase + r*256 + tid;
    atomicMin(&minbuf[ai], f2sort(m[r]));
  }
}

// ---- Chamfer finalize: d = a_sq + min_t; sum into acc[8]/acc[9]/acc[10] ----
__global__ __launch_bounds__(256)
void k_chamfin(const unsigned* __restrict__ minbuf, const float* __restrict__ s_src,
               const float* __restrict__ s_trg, const float* __restrict__ nv,
               float* __restrict__ acc, int Ns, int Nt) {
  int idx = blockIdx.x * 256 + threadIdx.x;
  const float* A; int li; float* dst; const unsigned* mb;
  if (idx < Ns)            { A = s_src; li = idx;        dst = &acc[8];  mb = minbuf; }
  else if (idx < Ns + Nt)  { A = s_trg; li = idx - Ns;   dst = &acc[9];  mb = minbuf + Ns; }
  else                     { A = nv;    li = idx - Ns - Nt; dst = &acc[10]; mb = minbuf + Ns + Nt; }
  float x = A[3*li], y = A[3*li+1], z = A[3*li+2];
  float d = x*x + y*y + z*z + sort2f(mb[li]);
  blockAccum(dst, d);
}

// ---- Final combine (matches reference accumulation order) ----
__global__ void k_combine(const float* __restrict__ acc, float* __restrict__ out,
                          int V, int F, int E, int P, int Ns, int Nt) {
  if (threadIdx.x != 0 || blockIdx.x != 0) return;
  float loss = 1.0f * (acc[8]/(float)Ns + acc[9]/(float)Nt);      // chamfer
  loss += 0.1f * ((acc[1] + acc[2]) / (float)F);                  // face
  loss += 0.1f * (acc[3] / (float)E);                             // edge
  loss += 0.1f * (acc[4] / (float)P);                             // normal
  loss += 0.1f * (acc[5] / (float)F);                             // smooth
  loss += 0.1f * (acc[6] / (float)V);                             // laplacian
  loss += 0.5f * (acc[7] / (3.0f * (float)V));                    // consistency
  loss += 0.1f * (2.0f * acc[10] / (float)V);                     // symmetry (dirs equal by flip isometry)
  loss += 5.0f * (acc[11] / (float)V);                            // penetration
  out[0] = loss;
}

extern "C" void kernel_launch(void* const* d_in, const int* in_sizes, int n_in,
                              void* d_out, int out_size, void* d_ws, size_t ws_size,
                              hipStream_t stream) {
  const float* verts   = (const float*)d_in[0];
  const float* deform  = (const float*)d_in[1];
  const float* bary    = (const float*)d_in[2];
  const float* s_trg   = (const float*)d_in[3];
  const float* vnorm   = (const float*)d_in[4];
  const int*   faces   = (const int*)d_in[5];
  const int*   edges   = (const int*)d_in[6];
  const int*   fpairs  = (const int*)d_in[7];
  const int*   sfi     = (const int*)d_in[8];
  float* out = (float*)d_out;

  const int V  = in_sizes[0] / 3;
  const int Ns = in_sizes[2] / 3;
  const int Nt = in_sizes[3] / 3;
  const int F  = in_sizes[5] / 3;
  const int E  = in_sizes[6] / 2;
  const int P  = in_sizes[7] / 2;

  float* ws = (float*)d_ws;
  float* acc  = ws;                         // 16
  float* nbr  = ws + 16;                    // 3V
  float* deg  = nbr + 3*V;                  // V
  float* vsum = deg + V;                    // 3V
  unsigned* minbuf = (unsigned*)(vsum + 3*V);       // Ns+Nt+V
  float* nv    = (float*)(minbuf + (Ns + Nt + V));  // 3V
  float* s_src = nv + 3*V;                  // 3Ns
  float* fn_u  = s_src + 3*Ns;              // 3F
  float* e012  = fn_u + 3*F;                // 3F
  float* elen  = e012 + 3*F;                // E

  hipMemsetAsync(acc, 0, (size_t)(16 + 7*V) * sizeof(float), stream);
  hipMemsetAsync(minbuf, 0xFF, (size_t)(Ns + Nt + V) * sizeof(unsigned), stream);

  k_prep_verts<<<V/256, 256, 0, stream>>>(verts, deform, vnorm, nv, acc);
  k_faces1<<<F/256, 256, 0, stream>>>(faces, nv, deform, e012, fn_u, vsum, acc, F);
  k_edges1<<<E/256, 256, 0, stream>>>(edges, nv, elen, nbr, deg, E);
  k_sample<<<Ns/256, 256, 0, stream>>>(sfi, faces, bary, nv, s_src);
  k_pairs<<<P/256, 256, 0, stream>>>(fpairs, fn_u, acc);
  k_pass2<<<(F + E)/256, 256, 0, stream>>>(e012, elen, acc, F);
  k_vfin<<<V/256, 256, 0, stream>>>(nbr, deg, vsum, nv, vnorm, acc);

  dim3 g1(Ns/1024, Nt/1024);   // src -> trg
  k_cham<<<g1, 256, 0, stream>>>(s_src, s_trg, minbuf, 1.0f);
  dim3 g2(Nt/1024, Ns/1024);   // trg -> src
  k_cham<<<g2, 256, 0, stream>>>(s_trg, s_src, minbuf + Ns, 1.0f);
  dim3 g3(V/1024, V/1024);     // new_verts -> flip(new_verts)
  k_cham<<<g3, 256, 0, stream>>>(nv, nv, minbuf + Ns + Nt, -1.0f);

  k_chamfin<<<(Ns + Nt + V)/256, 256, 0, stream>>>(minbuf, s_src, s_trg, nv, acc, Ns, Nt);
  k_combine<<<1, 64, 0, stream>>>(acc, out, V, F, E, P, Ns, Nt);
}

// Round 2
// 209.515 us; speedup vs baseline: 1.1988x; 1.1988x over previous
//
#include <hip/hip_runtime.h>

// SMPL2MeshOptimizer fused mesh loss, round 2.
// ws (floats): acc[16] | nbr[3V] | deg[V] | vsum[3V]  (zeroed by one memset)
//              | minbuf[Ns+Nt+V] u32 (init inside k_geom)
//              | nv[3V] | s_src[3Ns] | fn_unit[3F] | e012[3F] | elen[E]

#define MEPS 1e-6f

__device__ __forceinline__ float waveReduceAdd(float v) {
#pragma unroll
  for (int off = 32; off > 0; off >>= 1) v += __shfl_down(v, off, 64);
  return v;
}
__device__ __forceinline__ void blockAccum(float* dst, float v) {
  v = waveReduceAdd(v);
  if ((threadIdx.x & 63) == 0) atomicAdd(dst, v);
}
// monotonic float<->uint so atomicMin(u32) == float min
__device__ __forceinline__ unsigned f2sort(float f) {
  unsigned b = __float_as_uint(f);
  return (b & 0x80000000u) ? ~b : (b | 0x80000000u);
}
__device__ __forceinline__ float sort2f(unsigned s) {
  unsigned b = (s & 0x80000000u) ? (s & 0x7fffffffu) : ~s;
  return __uint_as_float(b);
}

// ---- Fused geometry pass: per-vertex, per-face, per-edge, per-sample, minbuf init.
// new_verts computed on-the-fly (verts+deform gathers) so there is NO dependency
// on a preceding per-vertex kernel.
__global__ __launch_bounds__(256)
void k_geom(const float* __restrict__ verts, const float* __restrict__ deform,
            const float* __restrict__ vnorm, const float* __restrict__ bary,
            const int* __restrict__ faces, const int* __restrict__ edges,
            const int* __restrict__ sfi,
            float* __restrict__ nv, float* __restrict__ s_src,
            float* __restrict__ e012, float* __restrict__ fn_unit,
            float* __restrict__ vsum, float* __restrict__ nbr, float* __restrict__ deg,
            float* __restrict__ elen, unsigned* __restrict__ minbuf,
            float* __restrict__ acc,
            int V, int F, int E, int Ns) {
  int idx = blockIdx.x * 256 + threadIdx.x;
  if (idx < V) {
    int i = idx;
    float dx = deform[3*i], dy = deform[3*i+1], dz = deform[3*i+2];
    float nx = verts[3*i] + dx, ny = verts[3*i+1] + dy, nz = verts[3*i+2] + dz;
    nv[3*i] = nx; nv[3*i+1] = ny; nv[3*i+2] = nz;
    float dot = dx*vnorm[3*i] + dy*vnorm[3*i+1] + dz*vnorm[3*i+2];
    blockAccum(&acc[11], fabsf(fminf(dot, -0.1f)));
  } else if (idx < V + F) {
    int f = idx - V;
    int i0 = faces[3*f], i1 = faces[3*f+1], i2 = faces[3*f+2];
    float d0x = deform[3*i0], d0y = deform[3*i0+1], d0z = deform[3*i0+2];
    float d1x = deform[3*i1], d1y = deform[3*i1+1], d1z = deform[3*i1+2];
    float d2x = deform[3*i2], d2y = deform[3*i2+1], d2z = deform[3*i2+2];
    float v0x = verts[3*i0]+d0x, v0y = verts[3*i0+1]+d0y, v0z = verts[3*i0+2]+d0z;
    float v1x = verts[3*i1]+d1x, v1y = verts[3*i1+1]+d1y, v1z = verts[3*i1+2]+d1z;
    float v2x = verts[3*i2]+d2x, v2y = verts[3*i2+1]+d2y, v2z = verts[3*i2+2]+d2z;
    float e0 = sqrtf((v0x-v1x)*(v0x-v1x)+(v0y-v1y)*(v0y-v1y)+(v0z-v1z)*(v0z-v1z));
    float e1 = sqrtf((v1x-v2x)*(v1x-v2x)+(v1y-v2y)*(v1y-v2y)+(v1z-v2z)*(v1z-v2z));
    float e2 = sqrtf((v2x-v0x)*(v2x-v0x)+(v2y-v0y)*(v2y-v0y)+(v2z-v0z)*(v2z-v0z));
    e012[f] = e0; e012[F+f] = e1; e012[2*F+f] = e2;
    float ax = v1x-v0x, ay = v1y-v0y, az = v1z-v0z;
    float bx = v2x-v0x, by = v2y-v0y, bz = v2z-v0z;
    float fnx = ay*bz - az*by, fny = az*bx - ax*bz, fnz = ax*by - ay*bx;
    float inv = 1.0f / (sqrtf(fnx*fnx+fny*fny+fnz*fnz) + MEPS);
    fn_unit[3*f] = fnx*inv; fn_unit[3*f+1] = fny*inv; fn_unit[3*f+2] = fnz*inv;
    atomicAdd(&vsum[3*i0], fnx); atomicAdd(&vsum[3*i0+1], fny); atomicAdd(&vsum[3*i0+2], fnz);
    atomicAdd(&vsum[3*i1], fnx); atomicAdd(&vsum[3*i1+1], fny); atomicAdd(&vsum[3*i1+2], fnz);
    atomicAdd(&vsum[3*i2], fnx); atomicAdd(&vsum[3*i2+1], fny); atomicAdd(&vsum[3*i2+2], fnz);
    float s0 = sqrtf(d0x*d0x + d0y*d0y + d0z*d0z);
    float s1 = sqrtf(d1x*d1x + d1y*d1y + d1z*d1z);
    float s2 = sqrtf(d2x*d2x + d2y*d2y + d2z*d2z);
    blockAccum(&acc[5], fabsf(s0-s1) + fabsf(s1-s2) + fabsf(s2-s0));
    blockAccum(&acc[0], e0 + e1 + e2);
    blockAccum(&acc[1], fabsf(e0-e1) + fabsf(e1-e2) + fabsf(e2-e0));
  } else if (idx < V + F + E) {
    int e = idx - V - F;
    int a = edges[2*e], b = edges[2*e+1];
    float pax = verts[3*a]+deform[3*a], pay = verts[3*a+1]+deform[3*a+1], paz = verts[3*a+2]+deform[3*a+2];
    float pbx = verts[3*b]+deform[3*b], pby = verts[3*b+1]+deform[3*b+1], pbz = verts[3*b+2]+deform[3*b+2];
    elen[e] = sqrtf((pax-pbx)*(pax-pbx)+(pay-pby)*(pay-pby)+(paz-pbz)*(paz-pbz));
    atomicAdd(&nbr[3*a], pbx); atomicAdd(&nbr[3*a+1], pby); atomicAdd(&nbr[3*a+2], pbz);
    atomicAdd(&nbr[3*b], pax); atomicAdd(&nbr[3*b+1], pay); atomicAdd(&nbr[3*b+2], paz);
    atomicAdd(&deg[a], 1.0f);  atomicAdd(&deg[b], 1.0f);
  } else if (idx < V + F + E + Ns) {
    int s = idx - V - F - E;
    int f = sfi[s];
    int i0 = faces[3*f], i1 = faces[3*f+1], i2 = faces[3*f+2];
    float w0 = bary[3*s], w1 = bary[3*s+1], w2 = bary[3*s+2];
    s_src[3*s]   = w0*(verts[3*i0]  +deform[3*i0])   + w1*(verts[3*i1]  +deform[3*i1])   + w2*(verts[3*i2]  +deform[3*i2]);
    s_src[3*s+1] = w0*(verts[3*i0+1]+deform[3*i0+1]) + w1*(verts[3*i1+1]+deform[3*i1+1]) + w2*(verts[3*i2+1]+deform[3*i2+1]);
    s_src[3*s+2] = w0*(verts[3*i0+2]+deform[3*i0+2]) + w1*(verts[3*i1+2]+deform[3*i1+2]) + w2*(verts[3*i2+2]+deform[3*i2+2]);
  } else {
    minbuf[idx - (V + F + E + Ns)] = 0xFFFFFFFFu;
  }
}

// ---- Fused second pass: face-pair normals, |e-avg|, (elen-avg)^2, per-vertex finalize.
__global__ __launch_bounds__(256)
void k_finish(const int* __restrict__ fpairs, const float* __restrict__ fn_unit,
              const float* __restrict__ e012, const float* __restrict__ elen,
              const float* __restrict__ nbr, const float* __restrict__ deg,
              const float* __restrict__ vsum, const float* __restrict__ nv,
              const float* __restrict__ vnorm, float* __restrict__ acc,
              int P, int F, int E, int V) {
  int idx = blockIdx.x * 256 + threadIdx.x;
  float avg = acc[0] / (3.0f * (float)F);
  if (idx < P) {
    int p = idx;
    int f0 = fpairs[2*p], f1 = fpairs[2*p+1];
    float d = fn_unit[3*f0]*fn_unit[3*f1] + fn_unit[3*f0+1]*fn_unit[3*f1+1]
            + fn_unit[3*f0+2]*fn_unit[3*f1+2];
    blockAccum(&acc[4], 1.0f - d);
  } else if (idx < P + F) {
    int f = idx - P;
    float e0 = e012[f], e1 = e012[F+f], e2 = e012[2*F+f];
    blockAccum(&acc[2], fabsf(e0-avg) + fabsf(e1-avg) + fabsf(e2-avg));
  } else if (idx < P + F + E) {
    int e = idx - P - F;
    float d = elen[e] - avg;
    blockAccum(&acc[3], d*d);
  } else {
    int i = idx - P - F - E;
    float inv = 1.0f / fmaxf(deg[i], 1.0f);
    float lx = nbr[3*i]*inv   - nv[3*i];
    float ly = nbr[3*i+1]*inv - nv[3*i+1];
    float lz = nbr[3*i+2]*inv - nv[3*i+2];
    blockAccum(&acc[6], sqrtf(lx*lx + ly*ly + lz*lz));
    float vx = vsum[3*i], vy = vsum[3*i+1], vz = vsum[3*i+2];
    float vinv = 1.0f / (sqrtf(vx*vx + vy*vy + vz*vz) + MEPS);
    float dx = vx*vinv - vnorm[3*i];
    float dy = vy*vinv - vnorm[3*i+1];
    float dz = vz*vinv - vnorm[3*i+2];
    blockAccum(&acc[7], dx*dx + dy*dy + dz*dz);
  }
}

// ---- Chamfer min tile: a-tile 1024 (4 rows/thread in regs) x b-tile 512 in LDS.
#define ATILE 1024
#define BTILE 512
__global__ __launch_bounds__(256)
void k_cham(const float* __restrict__ A, const float* __restrict__ B,
            unsigned* __restrict__ minbuf, float flipSign) {
  __shared__ float4 lds[BTILE];
  const int tid = threadIdx.x;
  const int aBase = blockIdx.x * ATILE + tid;
  const int b0 = blockIdx.y * BTILE;
  float ax[4], ay[4], az[4], m[4];
#pragma unroll
  for (int r = 0; r < 4; ++r) {
    int ai = aBase + r * 256;
    ax[r] = A[3*ai]; ay[r] = A[3*ai+1]; az[r] = A[3*ai+2];
    m[r] = 3.402823466e38f;
  }
#pragma unroll
  for (int s = 0; s < BTILE/256; ++s) {
    int bi = b0 + s*256 + tid;
    float bx = B[3*bi] * flipSign;
    float by = B[3*bi+1];
    float bz = B[3*bi+2];
    lds[s*256 + tid] = make_float4(-2.0f*bx, -2.0f*by, -2.0f*bz, bx*bx + by*by + bz*bz);
  }
  __syncthreads();
#pragma unroll 8
  for (int j = 0; j < BTILE; ++j) {
    float4 b = lds[j];
#pragma unroll
    for (int r = 0; r < 4; ++r)
      m[r] = fminf(m[r], fmaf(ax[r], b.x, fmaf(ay[r], b.y, fmaf(az[r], b.z, b.w))));
  }
#pragma unroll
  for (int r = 0; r < 4; ++r)
    atomicMin(&minbuf[aBase + r*256], f2sort(m[r]));
}

// ---- Chamfer finalize: d = |a|^2 + min_t ----
__global__ __launch_bounds__(256)
void k_chamfin(const unsigned* __restrict__ minbuf, const float* __restrict__ s_src,
               const float* __restrict__ s_trg, const float* __restrict__ nv,
               float* __restrict__ acc, int Ns, int Nt) {
  int idx = blockIdx.x * 256 + threadIdx.x;
  const float* A; int li; float* dst; const unsigned* mb;
  if (idx < Ns)            { A = s_src; li = idx;           dst = &acc[8];  mb = minbuf; }
  else if (idx < Ns + Nt)  { A = s_trg; li = idx - Ns;      dst = &acc[9];  mb = minbuf + Ns; }
  else                     { A = nv;    li = idx - Ns - Nt; dst = &acc[10]; mb = minbuf + Ns + Nt; }
  float x = A[3*li], y = A[3*li+1], z = A[3*li+2];
  blockAccum(dst, x*x + y*y + z*z + sort2f(mb[li]));
}

__global__ void k_combine(const float* __restrict__ acc, float* __restrict__ out,
                          int V, int F, int E, int P, int Ns, int Nt) {
  if (threadIdx.x != 0 || blockIdx.x != 0) return;
  float loss = acc[8]/(float)Ns + acc[9]/(float)Nt;               // chamfer
  loss += 0.1f * ((acc[1] + acc[2]) / (float)F);                  // face
  loss += 0.1f * (acc[3] / (float)E);                             // edge
  loss += 0.1f * (acc[4] / (float)P);                             // normal
  loss += 0.1f * (acc[5] / (float)F);                             // smooth
  loss += 0.1f * (acc[6] / (float)V);                             // laplacian
  loss += 0.5f * (acc[7] / (3.0f * (float)V));                    // consistency
  loss += 0.1f * (2.0f * acc[10] / (float)V);                     // symmetry (flip isometry)
  loss += 5.0f * (acc[11] / (float)V);                            // penetration
  out[0] = loss;
}

extern "C" void kernel_launch(void* const* d_in, const int* in_sizes, int n_in,
                              void* d_out, int out_size, void* d_ws, size_t ws_size,
                              hipStream_t stream) {
  const float* verts   = (const float*)d_in[0];
  const float* deform  = (const float*)d_in[1];
  const float* bary    = (const float*)d_in[2];
  const float* s_trg   = (const float*)d_in[3];
  const float* vnorm   = (const float*)d_in[4];
  const int*   faces   = (const int*)d_in[5];
  const int*   edges   = (const int*)d_in[6];
  const int*   fpairs  = (const int*)d_in[7];
  const int*   sfi     = (const int*)d_in[8];
  float* out = (float*)d_out;

  const int V  = in_sizes[0] / 3;
  const int Ns = in_sizes[2] / 3;
  const int Nt = in_sizes[3] / 3;
  const int F  = in_sizes[5] / 3;
  const int E  = in_sizes[6] / 2;
  const int P  = in_sizes[7] / 2;

  float* ws = (float*)d_ws;
  float* acc  = ws;                                  // 16
  float* nbr  = ws + 16;                             // 3V
  float* deg  = nbr + 3*V;                           // V
  float* vsum = deg + V;                             // 3V
  unsigned* minbuf = (unsigned*)(vsum + 3*V);        // Ns+Nt+V
  float* nv    = (float*)(minbuf + (Ns + Nt + V));   // 3V
  float* s_src = nv + 3*V;                           // 3Ns
  float* fn_u  = s_src + 3*Ns;                       // 3F
  float* e012  = fn_u + 3*F;                         // 3F
  float* elen  = e012 + 3*F;                         // E

  hipMemsetAsync(acc, 0, (size_t)(16 + 7*V) * sizeof(float), stream);

  int nGeom = V + F + E + Ns + (Ns + Nt + V);
  k_geom<<<nGeom/256, 256, 0, stream>>>(verts, deform, vnorm, bary, faces, edges, sfi,
                                        nv, s_src, e012, fn_u, vsum, nbr, deg, elen,
                                        minbuf, acc, V, F, E, Ns);
  int nFin = P + F + E + V;
  k_finish<<<nFin/256, 256, 0, stream>>>(fpairs, fn_u, e012, elen, nbr, deg, vsum,
                                         nv, vnorm, acc, P, F, E, V);

  k_cham<<<dim3(Ns/ATILE, Nt/BTILE), 256, 0, stream>>>(s_src, s_trg, minbuf, 1.0f);
  k_cham<<<dim3(Nt/ATILE, Ns/BTILE), 256, 0, stream>>>(s_trg, s_src, minbuf + Ns, 1.0f);
  k_cham<<<dim3(V/ATILE,  V/BTILE),  256, 0, stream>>>(nv, nv, minbuf + Ns + Nt, -1.0f);

  k_chamfin<<<(Ns + Nt + V)/256, 256, 0, stream>>>(minbuf, s_src, s_trg, nv, acc, Ns, Nt);
  k_combine<<<1, 64, 0, stream>>>(acc, out, V, F, E, P, Ns, Nt);
}